// Round 1
// baseline (328.486 us; speedup 1.0000x reference)
//
#include <hip/hip_runtime.h>
#include <cstdint>
#include <cstddef>

typedef unsigned short u16;
typedef __bf16 bf16x8 __attribute__((ext_vector_type(8)));
typedef float f32x4 __attribute__((ext_vector_type(4)));

// float -> bf16 (RNE), raw bits
__device__ __forceinline__ u16 f2bf(float f) {
    unsigned int x = __builtin_bit_cast(unsigned int, f);
    x += 0x7FFFu + ((x >> 16) & 1u);
    return (u16)(x >> 16);
}

// 16B load of 8 bf16 as MFMA fragment; memcpy => may-alias (safe vs u16 stores),
// assume_aligned(16) => single b128 load.
__device__ __forceinline__ bf16x8 ldfrag(const u16* p) {
    bf16x8 r;
    __builtin_memcpy(&r, (const u16*)__builtin_assume_aligned(p, 16), 16);
    return r;
}

__device__ __forceinline__ int4 ldg16(const u16* p) {
    int4 r;
    __builtin_memcpy(&r, (const u16*)__builtin_assume_aligned(p, 16), 16);
    return r;
}

__device__ __forceinline__ void st16(u16* p, int4 v) {
    __builtin_memcpy((u16*)__builtin_assume_aligned(p, 16), &v, 16);
}

// ---------------------------------------------------------------- cvt x->bf16
__global__ __launch_bounds__(256) void cvt_bf16(const float* __restrict__ in,
                                                u16* __restrict__ out, int n) {
    int i = (blockIdx.x * 256 + threadIdx.x) * 4;
    if (i >= n) return;
    float4 v = *reinterpret_cast<const float4*>(in + i);
    union { u16 e[4]; unsigned long long u; } w;
    w.e[0] = f2bf(v.x); w.e[1] = f2bf(v.y); w.e[2] = f2bf(v.z); w.e[3] = f2bf(v.w);
    *reinterpret_cast<unsigned long long*>(out + i) = w.u;
}

// ------------------------------------------------- W [768][2304] -> Wt bf16 [2304][768]
__global__ __launch_bounds__(256) void wt_transpose(const float* __restrict__ W,
                                                    u16* __restrict__ Wt) {
    const int R = 768, Ccols = 2304;
    __shared__ float tile[32][33];
    const int bx = blockIdx.x * 32;   // col of W
    const int by = blockIdx.y * 32;   // row of W
    const int tx = threadIdx.x & 31, ty = threadIdx.x >> 5;  // ty in 0..7
    #pragma unroll
    for (int i = 0; i < 32; i += 8)
        tile[ty + i][tx] = W[(size_t)(by + ty + i) * Ccols + bx + tx];
    __syncthreads();
    #pragma unroll
    for (int i = 0; i < 32; i += 8)
        Wt[(size_t)(bx + ty + i) * R + by + tx] = f2bf(tile[tx][ty + i]);
}

// ---------------------------------------------------------------- QKV GEMM
// C[M=8192][N=2304] = A[M][K=768] @ Wt^T + bias, bf16 in/out, fp32 acc.
__global__ __launch_bounds__(256) void qkv_gemm(const u16* __restrict__ A,
                                                const u16* __restrict__ Bt,   // [N][K]
                                                const float* __restrict__ bias,
                                                u16* __restrict__ C) {
    const int N = 2304, K = 768;
    __shared__ u16 sA[128 * 32];   // 8 KB
    __shared__ u16 sB[128 * 32];   // 8 KB
    const int t = threadIdx.x;
    const int wave = t >> 6, lane = t & 63;
    const int quad = lane >> 4, l16 = lane & 15;
    const int wr = wave >> 1, wc = wave & 1;            // 2x2 wave grid, 64x64 each
    const int m0 = blockIdx.y * 128, n0 = blockIdx.x * 128;
    const int lrow = t >> 1, lseg = t & 1;              // staging: 2 thr/row, 32B each

    f32x4 acc[4][4] = {};

    for (int k0 = 0; k0 < K; k0 += 32) {
        const u16* ga = A  + (size_t)(m0 + lrow) * K + k0 + lseg * 16;
        const u16* gb = Bt + (size_t)(n0 + lrow) * K + k0 + lseg * 16;
        int4 a0 = ldg16(ga), a1 = ldg16(ga + 8);
        int4 b0 = ldg16(gb), b1 = ldg16(gb + 8);
        __syncthreads();  // prev iter done reading LDS
        st16(sA + lrow * 32 + lseg * 16,     a0);
        st16(sA + lrow * 32 + lseg * 16 + 8, a1);
        st16(sB + lrow * 32 + lseg * 16,     b0);
        st16(sB + lrow * 32 + lseg * 16 + 8, b1);
        __syncthreads();
        bf16x8 af[4], bfr[4];
        #pragma unroll
        for (int i = 0; i < 4; ++i)
            af[i] = ldfrag(sA + (wr * 64 + i * 16 + l16) * 32 + quad * 8);
        #pragma unroll
        for (int j = 0; j < 4; ++j)
            bfr[j] = ldfrag(sB + (wc * 64 + j * 16 + l16) * 32 + quad * 8);
        #pragma unroll
        for (int i = 0; i < 4; ++i)
            #pragma unroll
            for (int j = 0; j < 4; ++j)
                acc[i][j] = __builtin_amdgcn_mfma_f32_16x16x32_bf16(af[i], bfr[j], acc[i][j], 0, 0, 0);
    }

    // epilogue: D[row=(lane>>4)*4+r][col=lane&15]  (m89-verified C/D layout)
    #pragma unroll
    for (int i = 0; i < 4; ++i)
        #pragma unroll
        for (int j = 0; j < 4; ++j) {
            const int col = n0 + wc * 64 + j * 16 + l16;
            const float bc = bias[col];
            #pragma unroll
            for (int r = 0; r < 4; ++r) {
                const int row = m0 + wr * 64 + i * 16 + quad * 4 + r;
                C[(size_t)row * N + col] = f2bf(acc[i][j][r] + bc);
            }
        }
}

// ---------------------------------------------------------------- attention
// One block = (b, h, 64-row Q tile). 4 waves x 16 Q-rows. No softmax: O += relu(mask(S))V.
__global__ __launch_bounds__(256) void attn_kernel(const u16* __restrict__ qkv,
                                                   float* __restrict__ out) {
    const int T = 2048, C3 = 2304, Cc = 768, Dh = 64;
    const int qt = blockIdx.x, h = blockIdx.y, b = blockIdx.z;
    const int t = threadIdx.x;
    const int wave = t >> 6, lane = t & 63;
    const int quad = lane >> 4, l16 = lane & 15;

    __shared__ u16 sVt[64 * 64];      // [d][token], stride 64 (bank-uniform for B-frag reads)
    __shared__ u16 sP[4 * 16 * 72];   // per-wave P tile [16 q][72], stride 72 (16B-aligned rows)

    const u16* qb = qkv + (size_t)b * T * C3 + (size_t)h * Dh;
    const u16* kb = qb + Cc;
    const u16* vb = qb + 2 * Cc;

    const int q0 = qt * 64;

    // Q fragments for this wave's 16 rows, held in regs for the whole K loop.
    // A-layout: A[m=lane&15][k=quad*8+j], contiguous d in global row-major -> direct 16B loads.
    bf16x8 aq0, aq1;
    {
        const u16* p = qb + (size_t)(q0 + wave * 16 + l16) * C3 + quad * 8;
        aq0 = ldfrag(p);
        aq1 = ldfrag(p + 32);
    }

    f32x4 oacc[4] = {};
    u16* myP = sP + wave * (16 * 72);

    for (int it = 0; it <= qt; ++it) {   // causal: only tiles with k0 <= q0
        const int k0 = it * 64;

        // ---- stage V transposed: sVt[d][tok]  (B-operand needs contiguous token)
        __syncthreads();  // prev iter done reading sVt
        {
            const int tok = t >> 2, ds4 = t & 3;
            const u16* vp = vb + (size_t)(k0 + tok) * C3;
            #pragma unroll
            for (int half = 0; half < 2; ++half) {
                const int d0 = (ds4 + half * 4) * 8;
                union { int4 v; u16 e[8]; } u;
                u.v = ldg16(vp + d0);
                #pragma unroll
                for (int i = 0; i < 8; ++i)
                    sVt[(d0 + i) * 64 + tok] = u.e[i];
            }
        }
        __syncthreads();

        // ---- S = Q K^T for this wave's 16 rows x 64 cols; mask+relu; P -> LDS (wave-private)
        #pragma unroll
        for (int kt = 0; kt < 4; ++kt) {
            // B-frag for K^T: lane holds K[token=l16+16kt][d=quad*8+j] -> contiguous, direct global
            const u16* kp = kb + (size_t)(k0 + kt * 16 + l16) * C3 + quad * 8;
            bf16x8 bk0 = ldfrag(kp);
            bf16x8 bk1 = ldfrag(kp + 32);
            f32x4 s = {};
            s = __builtin_amdgcn_mfma_f32_16x16x32_bf16(aq0, bk0, s, 0, 0, 0);
            s = __builtin_amdgcn_mfma_f32_16x16x32_bf16(aq1, bk1, s, 0, 0, 0);
            #pragma unroll
            for (int r = 0; r < 4; ++r) {
                const int qg = q0 + wave * 16 + quad * 4 + r;  // C/D row
                const int kg = k0 + kt * 16 + l16;             // C/D col
                const float v = (kg <= qg) ? fmaxf(s[r] * 0.125f, 0.0f) : 0.0f;
                myP[(quad * 4 + r) * 72 + kt * 16 + l16] = f2bf(v);
            }
        }

        // ---- O += P @ V   (P via LDS round-trip into A-layout; no barrier: wave-private)
        #pragma unroll
        for (int kk = 0; kk < 2; ++kk) {
            bf16x8 ap = ldfrag(myP + l16 * 72 + kk * 32 + quad * 8);
            #pragma unroll
            for (int dt = 0; dt < 4; ++dt) {
                bf16x8 bv = ldfrag(sVt + (dt * 16 + l16) * 64 + kk * 32 + quad * 8);
                oacc[dt] = __builtin_amdgcn_mfma_f32_16x16x32_bf16(ap, bv, oacc[dt], 0, 0, 0);
            }
        }
    }

    // ---- write O (fp32, C/D layout)
    #pragma unroll
    for (int dt = 0; dt < 4; ++dt)
        #pragma unroll
        for (int r = 0; r < 4; ++r) {
            const int tg = q0 + wave * 16 + quad * 4 + r;
            out[((size_t)b * T + tg) * Cc + h * Dh + dt * 16 + l16] = oacc[dt][r];
        }
}

// ---------------------------------------------------------------- launch
extern "C" void kernel_launch(void* const* d_in, const int* in_sizes, int n_in,
                              void* d_out, int out_size, void* d_ws, size_t ws_size,
                              hipStream_t stream) {
    const float* x    = (const float*)d_in[0];   // [4,2048,768]
    const float* W    = (const float*)d_in[1];   // [768,2304]
    const float* bias = (const float*)d_in[2];   // [2304]
    float* out = (float*)d_out;                  // [4,2048,768]

    char* ws = (char*)d_ws;
    const size_t xb_bytes = (size_t)8192 * 768 * 2;    // 12.6 MB
    const size_t wt_bytes = (size_t)2304 * 768 * 2;    //  3.5 MB
    u16* xb  = (u16*)ws;
    u16* Wt  = (u16*)(ws + xb_bytes);
    u16* qkv = (u16*)(ws + xb_bytes + wt_bytes);       // 37.7 MB [8192][2304]

    cvt_bf16<<<6144, 256, 0, stream>>>(x, xb, 8192 * 768);
    wt_transpose<<<dim3(72, 24), 256, 0, stream>>>(W, Wt);
    qkv_gemm<<<dim3(18, 64), 256, 0, stream>>>(xb, Wt, bias, qkv);
    attn_kernel<<<dim3(32, 12, 4), 256, 0, stream>>>(qkv, out);
}

// Round 2
// 247.009 us; speedup vs baseline: 1.3299x; 1.3299x over previous
//
#include <hip/hip_runtime.h>
#include <cstdint>
#include <cstddef>

typedef unsigned short u16;
typedef unsigned int u32;
typedef __bf16 bf16x8 __attribute__((ext_vector_type(8)));
typedef float f32x4 __attribute__((ext_vector_type(4)));

// float -> bf16 (RNE), raw bits
__device__ __forceinline__ u16 f2bf(float f) {
    unsigned int x = __builtin_bit_cast(unsigned int, f);
    x += 0x7FFFu + ((x >> 16) & 1u);
    return (u16)(x >> 16);
}

__device__ __forceinline__ bf16x8 ldfrag(const u16* p) {
    bf16x8 r;
    __builtin_memcpy(&r, (const u16*)__builtin_assume_aligned(p, 16), 16);
    return r;
}

__device__ __forceinline__ int4 ldg16(const u16* p) {
    int4 r;
    __builtin_memcpy(&r, (const u16*)__builtin_assume_aligned(p, 16), 16);
    return r;
}

// async global->LDS, 16B per lane; lds dest = wave-uniform base + lane*16
__device__ __forceinline__ void async16(u16* lds, const u16* g) {
    __builtin_amdgcn_global_load_lds(
        (const __attribute__((address_space(1))) void*)g,
        (__attribute__((address_space(3))) void*)lds,
        16, 0, 0);
}

// ---------------------------------------------------------------- cvt x->bf16
__global__ __launch_bounds__(256) void cvt_bf16(const float* __restrict__ in,
                                                u16* __restrict__ out, int n) {
    int i = (blockIdx.x * 256 + threadIdx.x) * 4;
    if (i >= n) return;
    float4 v = *reinterpret_cast<const float4*>(in + i);
    union { u16 e[4]; unsigned long long u; } w;
    w.e[0] = f2bf(v.x); w.e[1] = f2bf(v.y); w.e[2] = f2bf(v.z); w.e[3] = f2bf(v.w);
    *reinterpret_cast<unsigned long long*>(out + i) = w.u;
}

// ------------------------------------------------- W [768][2304] -> Wt bf16 [2304][768]
__global__ __launch_bounds__(256) void wt_transpose(const float* __restrict__ W,
                                                    u16* __restrict__ Wt) {
    const int R = 768, Ccols = 2304;
    __shared__ float tile[32][33];
    const int bx = blockIdx.x * 32;   // col of W
    const int by = blockIdx.y * 32;   // row of W
    const int tx = threadIdx.x & 31, ty = threadIdx.x >> 5;  // ty in 0..7
    #pragma unroll
    for (int i = 0; i < 32; i += 8)
        tile[ty + i][tx] = W[(size_t)(by + ty + i) * Ccols + bx + tx];
    __syncthreads();
    #pragma unroll
    for (int i = 0; i < 32; i += 8)
        Wt[(size_t)(bx + ty + i) * R + by + tx] = f2bf(tile[tx][ty + i]);
}

// ---------------------------------------------------------------- QKV GEMM
// C[M=8192][N=2304] = A[M][K=768] @ Wt^T + bias, bf16 in/out, fp32 acc.
// m97 pattern: global_load_lds width-16 staging, 128x128 tile, BK=32.
__global__ __launch_bounds__(256) void qkv_gemm(const u16* __restrict__ A,
                                                const u16* __restrict__ Bt,   // [N][K]
                                                const float* __restrict__ bias,
                                                u16* __restrict__ C) {
    const int N = 2304, K = 768;
    __shared__ u16 sA[128 * 32];   // 8 KB, row-major rowstride 32 u16
    __shared__ u16 sB[128 * 32];   // 8 KB
    const int t = threadIdx.x;
    const int wave = t >> 6, lane = t & 63;
    const int quad = lane >> 4, l16 = lane & 15;
    const int wr = wave >> 1, wc = wave & 1;            // 2x2 wave grid, 64x64 each
    const int m0 = blockIdx.y * 128, n0 = blockIdx.x * 128;

    // staging map: LDS byte o = row*64 + seg*16  ->  lane covers o = chunk + lane*16
    const int srow = wave * 32 + (lane >> 2);   // + j*16
    const int sseg = lane & 3;

    f32x4 acc[4][4] = {};

    for (int k0 = 0; k0 < K; k0 += 32) {
        __syncthreads();  // prev iter's ds_reads done before overwrite
        #pragma unroll
        for (int j = 0; j < 2; ++j) {
            const int row = srow + j * 16;
            async16(sA + wave * 1024 + j * 512,
                    A + (size_t)(m0 + row) * K + k0 + sseg * 8);
            async16(sB + wave * 1024 + j * 512,
                    Bt + (size_t)(n0 + row) * K + k0 + sseg * 8);
        }
        __syncthreads();  // vmcnt(0) drain -> LDS visible

        bf16x8 af[4], bfr[4];
        #pragma unroll
        for (int i = 0; i < 4; ++i)
            af[i] = ldfrag(sA + (wr * 64 + i * 16 + l16) * 32 + quad * 8);
        #pragma unroll
        for (int j = 0; j < 4; ++j)
            bfr[j] = ldfrag(sB + (wc * 64 + j * 16 + l16) * 32 + quad * 8);
        #pragma unroll
        for (int i = 0; i < 4; ++i)
            #pragma unroll
            for (int j = 0; j < 4; ++j)
                acc[i][j] = __builtin_amdgcn_mfma_f32_16x16x32_bf16(af[i], bfr[j], acc[i][j], 0, 0, 0);
    }

    // epilogue: D[row=(lane>>4)*4+r][col=lane&15]
    #pragma unroll
    for (int i = 0; i < 4; ++i)
        #pragma unroll
        for (int j = 0; j < 4; ++j) {
            const int col = n0 + wc * 64 + j * 16 + l16;
            const float bc = bias[col];
            #pragma unroll
            for (int r = 0; r < 4; ++r) {
                const int row = m0 + wr * 64 + i * 16 + quad * 4 + r;
                C[(size_t)row * N + col] = f2bf(acc[i][j][r] + bc);
            }
        }
}

// ---------------------------------------------------------------- attention
// Triangular-paired: block = (b, h, Q-tiles qa and 31-qa). 33 tile-computations
// per block (uniform). Shared V stage + shared K frags serve both Q tiles.
__global__ __launch_bounds__(256) void attn_kernel(const u16* __restrict__ qkv,
                                                   float* __restrict__ out) {
    const int T = 2048, C3 = 2304, Cc = 768, Dh = 64;
    const int qa = blockIdx.x;           // 0..15
    const int qb = 31 - qa;              // partner tile (>= qa)
    const int h = blockIdx.y, b = blockIdx.z;
    const int t = threadIdx.x;
    const int wave = t >> 6, lane = t & 63;
    const int quad = lane >> 4, l16 = lane & 15;

    // V^T as packed token-pairs: sVt[d][tokpair], rowwords=36 (144B rows, 16B aligned)
    __shared__ u32 sVt[64 * 36];              // 9216 B
    __shared__ u16 sP[4 * 32 * 72];           // per-wave P: rows 0-15 tile a, 16-31 tile b

    const u16* qbase = qkv + (size_t)b * T * C3 + (size_t)h * Dh;
    const u16* kbase = qbase + Cc;
    const u16* vbase = qbase + 2 * Cc;

    // Q fragments (A-layout: row=l16, k=quad*8+j) for both tiles, held all loop
    bf16x8 aqa0, aqa1, aqb0, aqb1;
    {
        const u16* pa = qbase + (size_t)(qa * 64 + wave * 16 + l16) * C3 + quad * 8;
        const u16* pb = qbase + (size_t)(qb * 64 + wave * 16 + l16) * C3 + quad * 8;
        aqa0 = ldfrag(pa); aqa1 = ldfrag(pa + 32);
        aqb0 = ldfrag(pb); aqb1 = ldfrag(pb + 32);
    }

    f32x4 oa[4] = {}, ob[4] = {};
    u16* myP = sP + wave * (32 * 72);

    const int tp = t & 31;        // token pair
    const int dg = t >> 5;        // d group (0..7), 8 d each

    for (int it = 0; it <= qb; ++it) {
        const int k0 = it * 64;
        const bool act_a = (it <= qa);

        // ---- stage V tile as transposed token-pairs (2-way-max bank pattern)
        __syncthreads();  // prev iter done reading sVt
        {
            const u16* vp0 = vbase + (size_t)(k0 + 2 * tp) * C3 + dg * 8;
            union { int4 v; u16 e[8]; } ua, ub;
            ua.v = ldg16(vp0);
            ub.v = ldg16(vp0 + C3);
            #pragma unroll
            for (int i = 0; i < 8; ++i)
                sVt[(dg * 8 + i) * 36 + tp] = (u32)ua.e[i] | ((u32)ub.e[i] << 16);
        }
        __syncthreads();

        // ---- S = Q K^T ; K frag loaded once, used by both tiles; mask+relu -> P
        #pragma unroll
        for (int kt = 0; kt < 4; ++kt) {
            const int kg = k0 + kt * 16 + l16;
            const u16* kp = kbase + (size_t)kg * C3 + quad * 8;
            bf16x8 bk0 = ldfrag(kp);
            bf16x8 bk1 = ldfrag(kp + 32);
            // tile b (always active: it <= qb)
            {
                f32x4 s = {};
                s = __builtin_amdgcn_mfma_f32_16x16x32_bf16(aqb0, bk0, s, 0, 0, 0);
                s = __builtin_amdgcn_mfma_f32_16x16x32_bf16(aqb1, bk1, s, 0, 0, 0);
                #pragma unroll
                for (int r = 0; r < 4; ++r) {
                    const int qg = qb * 64 + wave * 16 + quad * 4 + r;
                    const float v = (kg <= qg) ? fmaxf(s[r] * 0.125f, 0.0f) : 0.0f;
                    myP[(16 + quad * 4 + r) * 72 + kt * 16 + l16] = f2bf(v);
                }
            }
            if (act_a) {
                f32x4 s = {};
                s = __builtin_amdgcn_mfma_f32_16x16x32_bf16(aqa0, bk0, s, 0, 0, 0);
                s = __builtin_amdgcn_mfma_f32_16x16x32_bf16(aqa1, bk1, s, 0, 0, 0);
                #pragma unroll
                for (int r = 0; r < 4; ++r) {
                    const int qg = qa * 64 + wave * 16 + quad * 4 + r;
                    const float v = (kg <= qg) ? fmaxf(s[r] * 0.125f, 0.0f) : 0.0f;
                    myP[(quad * 4 + r) * 72 + kt * 16 + l16] = f2bf(v);
                }
            }
        }

        // ---- O += P @ V  (wave-private P round-trip; bv frags shared by both tiles)
        #pragma unroll
        for (int kk = 0; kk < 2; ++kk) {
            bf16x8 apb = ldfrag(myP + (16 + l16) * 72 + kk * 32 + quad * 8);
            bf16x8 apa;
            if (act_a) apa = ldfrag(myP + l16 * 72 + kk * 32 + quad * 8);
            #pragma unroll
            for (int dt = 0; dt < 4; ++dt) {
                bf16x8 bv = ldfrag((const u16*)(sVt + (dt * 16 + l16) * 36 + kk * 16 + quad * 4));
                ob[dt] = __builtin_amdgcn_mfma_f32_16x16x32_bf16(apb, bv, ob[dt], 0, 0, 0);
                if (act_a)
                    oa[dt] = __builtin_amdgcn_mfma_f32_16x16x32_bf16(apa, bv, oa[dt], 0, 0, 0);
            }
        }
    }

    // ---- write O (fp32, C/D layout) for both tiles
    #pragma unroll
    for (int dt = 0; dt < 4; ++dt)
        #pragma unroll
        for (int r = 0; r < 4; ++r) {
            const int tga = qa * 64 + wave * 16 + quad * 4 + r;
            const int tgb = qb * 64 + wave * 16 + quad * 4 + r;
            const int c = h * Dh + dt * 16 + l16;
            out[((size_t)b * T + tga) * Cc + c] = oa[dt][r];
            out[((size_t)b * T + tgb) * Cc + c] = ob[dt][r];
        }
}

// ---------------------------------------------------------------- launch
extern "C" void kernel_launch(void* const* d_in, const int* in_sizes, int n_in,
                              void* d_out, int out_size, void* d_ws, size_t ws_size,
                              hipStream_t stream) {
    const float* x    = (const float*)d_in[0];   // [4,2048,768]
    const float* W    = (const float*)d_in[1];   // [768,2304]
    const float* bias = (const float*)d_in[2];   // [2304]
    float* out = (float*)d_out;                  // [4,2048,768]

    char* ws = (char*)d_ws;
    const size_t xb_bytes = (size_t)8192 * 768 * 2;    // 12.6 MB
    const size_t wt_bytes = (size_t)2304 * 768 * 2;    //  3.5 MB
    u16* xb  = (u16*)ws;
    u16* Wt  = (u16*)(ws + xb_bytes);
    u16* qkv = (u16*)(ws + xb_bytes + wt_bytes);       // 37.7 MB [8192][2304]

    cvt_bf16<<<6144, 256, 0, stream>>>(x, xb, 8192 * 768);
    wt_transpose<<<dim3(72, 24), 256, 0, stream>>>(W, Wt);
    qkv_gemm<<<dim3(18, 64), 256, 0, stream>>>(xb, Wt, bias, qkv);
    attn_kernel<<<dim3(16, 12, 4), 256, 0, stream>>>(qkv, out);
}

// Round 3
// 195.089 us; speedup vs baseline: 1.6838x; 1.2661x over previous
//
#include <hip/hip_runtime.h>
#include <cstdint>
#include <cstddef>

typedef unsigned short u16;
typedef unsigned int u32;
typedef __bf16 bf16x8 __attribute__((ext_vector_type(8)));
typedef float f32x4 __attribute__((ext_vector_type(4)));

// float -> bf16 (RNE), raw bits
__device__ __forceinline__ u16 f2bf(float f) {
    unsigned int x = __builtin_bit_cast(unsigned int, f);
    x += 0x7FFFu + ((x >> 16) & 1u);
    return (u16)(x >> 16);
}

__device__ __forceinline__ bf16x8 ldfrag(const u16* p) {
    bf16x8 r;
    __builtin_memcpy(&r, (const u16*)__builtin_assume_aligned(p, 16), 16);
    return r;
}

__device__ __forceinline__ int4 ldg16(const u16* p) {
    int4 r;
    __builtin_memcpy(&r, (const u16*)__builtin_assume_aligned(p, 16), 16);
    return r;
}

// async global->LDS, 16B per lane; lds dest = wave-uniform base + lane*16
__device__ __forceinline__ void async16(u16* lds, const u16* g) {
    __builtin_amdgcn_global_load_lds(
        (const __attribute__((address_space(1))) void*)g,
        (__attribute__((address_space(3))) void*)lds,
        16, 0, 0);
}

// ---------------------------------------------------------------- cvt x->bf16
__global__ __launch_bounds__(256) void cvt_bf16(const float* __restrict__ in,
                                                u16* __restrict__ out, int n) {
    int i = (blockIdx.x * 256 + threadIdx.x) * 4;
    if (i >= n) return;
    float4 v = *reinterpret_cast<const float4*>(in + i);
    union { u16 e[4]; unsigned long long u; } w;
    w.e[0] = f2bf(v.x); w.e[1] = f2bf(v.y); w.e[2] = f2bf(v.z); w.e[3] = f2bf(v.w);
    *reinterpret_cast<unsigned long long*>(out + i) = w.u;
}

// ------------------------------------------------- W [768][2304] -> Wt bf16 [2304][768]
__global__ __launch_bounds__(256) void wt_transpose(const float* __restrict__ W,
                                                    u16* __restrict__ Wt) {
    const int R = 768, Ccols = 2304;
    __shared__ float tile[32][33];
    const int bx = blockIdx.x * 32;   // col of W
    const int by = blockIdx.y * 32;   // row of W
    const int tx = threadIdx.x & 31, ty = threadIdx.x >> 5;  // ty in 0..7
    #pragma unroll
    for (int i = 0; i < 32; i += 8)
        tile[ty + i][tx] = W[(size_t)(by + ty + i) * Ccols + bx + tx];
    __syncthreads();
    #pragma unroll
    for (int i = 0; i < 32; i += 8)
        Wt[(size_t)(bx + ty + i) * R + by + tx] = f2bf(tile[tx][ty + i]);
}

// ---------------------------------------------------------------- QKV GEMM
// C[M=8192][N=2304] = A[M][K=768] @ Wt^T + bias, bf16 in/out, fp32 acc.
// Q columns (n<768) are pre-scaled by 0.125 (attention score scale, exact pow2).
__global__ __launch_bounds__(256) void qkv_gemm(const u16* __restrict__ A,
                                                const u16* __restrict__ Bt,   // [N][K]
                                                const float* __restrict__ bias,
                                                u16* __restrict__ C) {
    const int N = 2304, K = 768;
    __shared__ __align__(16) u16 sA[128 * 32];   // 8 KB
    __shared__ __align__(16) u16 sB[128 * 32];   // 8 KB
    const int t = threadIdx.x;
    const int wave = t >> 6, lane = t & 63;
    const int quad = lane >> 4, l16 = lane & 15;
    const int wr = wave >> 1, wc = wave & 1;            // 2x2 wave grid, 64x64 each
    const int m0 = blockIdx.y * 128, n0 = blockIdx.x * 128;

    const int srow = wave * 32 + (lane >> 2);   // + j*16
    const int sseg = lane & 3;

    f32x4 acc[4][4] = {};

    for (int k0 = 0; k0 < K; k0 += 32) {
        __syncthreads();
        #pragma unroll
        for (int j = 0; j < 2; ++j) {
            const int row = srow + j * 16;
            async16(sA + wave * 1024 + j * 512,
                    A + (size_t)(m0 + row) * K + k0 + sseg * 8);
            async16(sB + wave * 1024 + j * 512,
                    Bt + (size_t)(n0 + row) * K + k0 + sseg * 8);
        }
        __syncthreads();

        bf16x8 af[4], bfr[4];
        #pragma unroll
        for (int i = 0; i < 4; ++i)
            af[i] = ldfrag(sA + (wr * 64 + i * 16 + l16) * 32 + quad * 8);
        #pragma unroll
        for (int j = 0; j < 4; ++j)
            bfr[j] = ldfrag(sB + (wc * 64 + j * 16 + l16) * 32 + quad * 8);
        #pragma unroll
        for (int i = 0; i < 4; ++i)
            #pragma unroll
            for (int j = 0; j < 4; ++j)
                acc[i][j] = __builtin_amdgcn_mfma_f32_16x16x32_bf16(af[i], bfr[j], acc[i][j], 0, 0, 0);
    }

    #pragma unroll
    for (int i = 0; i < 4; ++i)
        #pragma unroll
        for (int j = 0; j < 4; ++j) {
            const int col = n0 + wc * 64 + j * 16 + l16;
            const float bc = bias[col];
            const float scale = (col < 768) ? 0.125f : 1.0f;   // uniform per j-block
            #pragma unroll
            for (int r = 0; r < 4; ++r) {
                const int row = m0 + wr * 64 + i * 16 + quad * 4 + r;
                C[(size_t)row * N + col] = f2bf((acc[i][j][r] + bc) * scale);
            }
        }
}

// ---------------------------------------------------------------- attention
// Triangular-paired + CU-balanced + single-barrier pipelined K/V double buffer.
__global__ __launch_bounds__(256) void attn_kernel(const u16* __restrict__ qkv,
                                                   float* __restrict__ out) {
    const int T = 2048, C3 = 2304, Cc = 768, Dh = 64;

    // balanced decode: CU's co-resident blocks (stride 256) get qa = {x, 15-x, (x+8)&15}
    const int bid = blockIdx.x;          // 0..767
    const int rr = bid >> 8;             // 0..2
    const int ss = bid & 255;
    const int x = ss & 15;
    const int qa = (rr == 0) ? x : (rr == 1) ? (15 - x) : ((x + 8) & 15);
    const int qb = 31 - qa;
    const int hb = (ss >> 4) + (rr << 4);   // 0..47
    const int h = hb % 12, b = hb / 12;

    const int t = threadIdx.x;
    const int wave = t >> 6, lane = t & 63;
    const int quad = lane >> 4, l16 = lane & 15;

    __shared__ __align__(16) u16 sK[2][64 * 64];    // 16 KB, XOR-chunk-swizzled rows
    __shared__ __align__(16) u32 sVt[2][64 * 36];   // 18 KB, [d][tokpair] packed
    __shared__ __align__(16) u16 sP[4 * 32 * 72];   // 18 KB, per-wave P

    const u16* qbase = qkv + (size_t)b * T * C3 + (size_t)h * Dh;
    const u16* kbase = qbase + Cc;
    const u16* vbase = qbase + 2 * Cc;

    // Q fragments (A-layout) for both tiles; score scale pre-folded in GEMM.
    bf16x8 aqa0, aqa1, aqb0, aqb1;
    {
        const u16* pa = qbase + (size_t)(qa * 64 + wave * 16 + l16) * C3 + quad * 8;
        const u16* pb = qbase + (size_t)(qb * 64 + wave * 16 + l16) * C3 + quad * 8;
        aqa0 = ldfrag(pa); aqa1 = ldfrag(pa + 32);
        aqb0 = ldfrag(pb); aqb1 = ldfrag(pb + 32);
    }

    f32x4 oa[4] = {}, ob[4] = {};
    u16* myP = sP + wave * (32 * 72);

    // V staging map: thread handles token-pair tp, d-chunk dg
    const int tp = t & 31, dg = t >> 5;
    // K staging map (async16): row = t>>3 (+32), chunk XOR-swizzled by row&7
    const int krow = t >> 3;
    const int kchunk = (t & 7) ^ (krow & 7);

    int4 v0r, v1r;
    auto loadV = [&](int it) {
        const u16* vp = vbase + (size_t)(it * 64 + 2 * tp) * C3 + dg * 8;
        v0r = ldg16(vp);
        v1r = ldg16(vp + C3);
    };
    auto stageK = [&](int it, int bi) {
        const u16* g0 = kbase + (size_t)(it * 64 + krow) * C3 + kchunk * 8;
        const u16* g1 = kbase + (size_t)(it * 64 + 32 + krow) * C3 + kchunk * 8;
        async16(&sK[bi][0] + wave * 512, g0);
        async16(&sK[bi][2048] + wave * 512, g1);
    };
    auto writeV = [&](int bi) {
        union { int4 v; u16 e[8]; } ua, ub;
        ua.v = v0r; ub.v = v1r;
        #pragma unroll
        for (int i = 0; i < 8; ++i)
            sVt[bi][(dg * 8 + i) * 36 + tp] = (u32)ua.e[i] | ((u32)ub.e[i] << 16);
    };

    // prologue: fill buffer 0
    loadV(0);
    stageK(0, 0);
    writeV(0);
    __syncthreads();

    int buf = 0;
    for (int it = 0; it <= qb; ++it) {
        const bool more = (it < qb);
        if (more) { loadV(it + 1); stageK(it + 1, buf ^ 1); }

        const bool act_a = (it <= qa);
        const bool edge_a = (it == qa), edge_b = (it == qb);
        const u16* sKb = sK[buf];
        const u32* sVb = sVt[buf];

        // ---- S = Q K^T ; relu (+ causal mask on diagonal tile only); -> P (LDS)
        #pragma unroll
        for (int kt = 0; kt < 4; ++kt) {
            const int tok = kt * 16 + l16;
            const int sw = tok & 7;
            bf16x8 bk0 = ldfrag(sKb + tok * 64 + ((quad ^ sw) << 3));
            bf16x8 bk1 = ldfrag(sKb + tok * 64 + (((quad + 4) ^ sw) << 3));
            {
                f32x4 s = {};
                s = __builtin_amdgcn_mfma_f32_16x16x32_bf16(aqb0, bk0, s, 0, 0, 0);
                s = __builtin_amdgcn_mfma_f32_16x16x32_bf16(aqb1, bk1, s, 0, 0, 0);
                #pragma unroll
                for (int r = 0; r < 4; ++r) {
                    float v = fmaxf(s[r], 0.0f);
                    if (edge_b) {                       // wave-uniform branch
                        const int qloc = wave * 16 + quad * 4 + r;
                        if (tok > qloc) v = 0.0f;
                    }
                    myP[(16 + quad * 4 + r) * 72 + kt * 16 + l16] = f2bf(v);
                }
            }
            if (act_a) {
                f32x4 s = {};
                s = __builtin_amdgcn_mfma_f32_16x16x32_bf16(aqa0, bk0, s, 0, 0, 0);
                s = __builtin_amdgcn_mfma_f32_16x16x32_bf16(aqa1, bk1, s, 0, 0, 0);
                #pragma unroll
                for (int r = 0; r < 4; ++r) {
                    float v = fmaxf(s[r], 0.0f);
                    if (edge_a) {
                        const int qloc = wave * 16 + quad * 4 + r;
                        if (tok > qloc) v = 0.0f;
                    }
                    myP[(quad * 4 + r) * 72 + kt * 16 + l16] = f2bf(v);
                }
            }
        }

        // ---- O += P @ V (wave-private P; V frags shared by both tiles)
        #pragma unroll
        for (int kk = 0; kk < 2; ++kk) {
            bf16x8 apb = ldfrag(myP + (16 + l16) * 72 + kk * 32 + quad * 8);
            bf16x8 apa;
            if (act_a) apa = ldfrag(myP + l16 * 72 + kk * 32 + quad * 8);
            #pragma unroll
            for (int dt = 0; dt < 4; ++dt) {
                bf16x8 bv = ldfrag((const u16*)(sVb + (dt * 16 + l16) * 36 + kk * 16 + quad * 4));
                ob[dt] = __builtin_amdgcn_mfma_f32_16x16x32_bf16(apb, bv, ob[dt], 0, 0, 0);
                if (act_a)
                    oa[dt] = __builtin_amdgcn_mfma_f32_16x16x32_bf16(apa, bv, oa[dt], 0, 0, 0);
            }
        }

        if (more) writeV(buf ^ 1);   // V(it+1) regs -> back buffer (after compute)
        __syncthreads();             // drains asyncs (vmcnt0) + LDS writes
        buf ^= 1;
    }

    // ---- write O (fp32, C/D layout) for both tiles
    #pragma unroll
    for (int dt = 0; dt < 4; ++dt)
        #pragma unroll
        for (int r = 0; r < 4; ++r) {
            const int tga = qa * 64 + wave * 16 + quad * 4 + r;
            const int tgb = qb * 64 + wave * 16 + quad * 4 + r;
            const int c = h * Dh + dt * 16 + l16;
            out[((size_t)b * T + tga) * Cc + c] = oa[dt][r];
            out[((size_t)b * T + tgb) * Cc + c] = ob[dt][r];
        }
}

// ---------------------------------------------------------------- launch
extern "C" void kernel_launch(void* const* d_in, const int* in_sizes, int n_in,
                              void* d_out, int out_size, void* d_ws, size_t ws_size,
                              hipStream_t stream) {
    const float* x    = (const float*)d_in[0];   // [4,2048,768]
    const float* W    = (const float*)d_in[1];   // [768,2304]
    const float* bias = (const float*)d_in[2];   // [2304]
    float* out = (float*)d_out;                  // [4,2048,768]

    char* ws = (char*)d_ws;
    const size_t xb_bytes = (size_t)8192 * 768 * 2;    // 12.6 MB
    const size_t wt_bytes = (size_t)2304 * 768 * 2;    //  3.5 MB
    u16* xb  = (u16*)ws;
    u16* Wt  = (u16*)(ws + xb_bytes);
    u16* qkv = (u16*)(ws + xb_bytes + wt_bytes);       // 37.7 MB [8192][2304]

    cvt_bf16<<<6144, 256, 0, stream>>>(x, xb, 8192 * 768);
    wt_transpose<<<dim3(72, 24), 256, 0, stream>>>(W, Wt);
    qkv_gemm<<<dim3(18, 64), 256, 0, stream>>>(xb, Wt, bias, qkv);
    attn_kernel<<<768, 256, 0, stream>>>(qkv, out);
}

// Round 4
// 186.937 us; speedup vs baseline: 1.7572x; 1.0436x over previous
//
#include <hip/hip_runtime.h>
#include <cstdint>
#include <cstddef>

typedef unsigned short u16;
typedef unsigned int u32;
typedef __bf16 bf16x8 __attribute__((ext_vector_type(8)));
typedef float f32x4 __attribute__((ext_vector_type(4)));

// float -> bf16 (RNE), raw bits
__device__ __forceinline__ u16 f2bf(float f) {
    unsigned int x = __builtin_bit_cast(unsigned int, f);
    x += 0x7FFFu + ((x >> 16) & 1u);
    return (u16)(x >> 16);
}

__device__ __forceinline__ bf16x8 ldfrag(const u16* p) {
    bf16x8 r;
    __builtin_memcpy(&r, (const u16*)__builtin_assume_aligned(p, 16), 16);
    return r;
}

__device__ __forceinline__ int4 ldg16(const u16* p) {
    int4 r;
    __builtin_memcpy(&r, (const u16*)__builtin_assume_aligned(p, 16), 16);
    return r;
}

// async global->LDS, 16B per lane; lds dest = wave-uniform base + lane*16
__device__ __forceinline__ void async16(u16* lds, const u16* g) {
    __builtin_amdgcn_global_load_lds(
        (const __attribute__((address_space(1))) void*)g,
        (__attribute__((address_space(3))) void*)lds,
        16, 0, 0);
}

// ---------------------------------------------------------------- cvt x->bf16
__global__ __launch_bounds__(256) void cvt_bf16(const float* __restrict__ in,
                                                u16* __restrict__ out, int n) {
    int i = (blockIdx.x * 256 + threadIdx.x) * 4;
    if (i >= n) return;
    float4 v = *reinterpret_cast<const float4*>(in + i);
    union { u16 e[4]; unsigned long long u; } w;
    w.e[0] = f2bf(v.x); w.e[1] = f2bf(v.y); w.e[2] = f2bf(v.z); w.e[3] = f2bf(v.w);
    *reinterpret_cast<unsigned long long*>(out + i) = w.u;
}

// ------------------------------------------------- W [768][2304] -> Wt bf16 [2304][768]
__global__ __launch_bounds__(256) void wt_transpose(const float* __restrict__ W,
                                                    u16* __restrict__ Wt) {
    const int R = 768, Ccols = 2304;
    __shared__ float tile[32][33];
    const int bx = blockIdx.x * 32;
    const int by = blockIdx.y * 32;
    const int tx = threadIdx.x & 31, ty = threadIdx.x >> 5;
    #pragma unroll
    for (int i = 0; i < 32; i += 8)
        tile[ty + i][tx] = W[(size_t)(by + ty + i) * Ccols + bx + tx];
    __syncthreads();
    #pragma unroll
    for (int i = 0; i < 32; i += 8)
        Wt[(size_t)(bx + ty + i) * R + by + tx] = f2bf(tile[tx][ty + i]);
}

// ---------------------------------------------------------------- QKV GEMM
// C[M=8192][N=2304] = A[M][K=768] @ Wt^T + bias. BK=64 (m97 config), XOR swizzle.
// Q columns (n<768) pre-scaled by 0.125.
__global__ __launch_bounds__(256) void qkv_gemm(const u16* __restrict__ A,
                                                const u16* __restrict__ Bt,   // [N][K]
                                                const float* __restrict__ bias,
                                                u16* __restrict__ C) {
    const int N = 2304, K = 768;
    __shared__ __align__(16) u16 sA[128 * 64];   // 16 KB, chunk ^= row&7
    __shared__ __align__(16) u16 sB[128 * 64];   // 16 KB
    const int t = threadIdx.x;
    const int wave = t >> 6, lane = t & 63;
    const int quad = lane >> 4, l16 = lane & 15;
    const int wr = wave >> 1, wc = wave & 1;
    const int m0 = blockIdx.y * 128, n0 = blockIdx.x * 128;

    // staging: call j covers rows j*32 + wave*8 + (lane>>3), stored chunk lane&7
    const int srow_base = wave * 8 + (lane >> 3);
    const int schunk = lane & 7;
    const int swz = (lane >> 3) & 7;   // row&7 (j*32, wave*8 are mult of 8)

    f32x4 acc[4][4] = {};

    for (int k0 = 0; k0 < K; k0 += 64) {
        __syncthreads();
        #pragma unroll
        for (int j = 0; j < 4; ++j) {
            const int row = j * 32 + srow_base;
            const int dch = schunk ^ swz;
            async16(sA + j * 2048 + wave * 512, A + (size_t)(m0 + row) * K + k0 + dch * 8);
            async16(sB + j * 2048 + wave * 512, Bt + (size_t)(n0 + row) * K + k0 + dch * 8);
        }
        __syncthreads();

        bf16x8 af[4][2], bfr[4][2];
        const int rsw = l16 & 7;
        #pragma unroll
        for (int i = 0; i < 4; ++i)
            #pragma unroll
            for (int h = 0; h < 2; ++h) {
                af[i][h] = ldfrag(sA + (wr * 64 + i * 16 + l16) * 64 + (((h * 4 + quad) ^ rsw) << 3));
                bfr[i][h] = ldfrag(sB + (wc * 64 + i * 16 + l16) * 64 + (((h * 4 + quad) ^ rsw) << 3));
            }
        #pragma unroll
        for (int h = 0; h < 2; ++h)
            #pragma unroll
            for (int i = 0; i < 4; ++i)
                #pragma unroll
                for (int j = 0; j < 4; ++j)
                    acc[i][j] = __builtin_amdgcn_mfma_f32_16x16x32_bf16(af[i][h], bfr[j][h], acc[i][j], 0, 0, 0);
    }

    #pragma unroll
    for (int i = 0; i < 4; ++i)
        #pragma unroll
        for (int j = 0; j < 4; ++j) {
            const int col = n0 + wc * 64 + j * 16 + l16;
            const float bc = bias[col];
            const float scale = (col < 768) ? 0.125f : 1.0f;
            #pragma unroll
            for (int r = 0; r < 4; ++r) {
                const int row = m0 + wr * 64 + i * 16 + quad * 4 + r;
                C[(size_t)row * N + col] = f2bf((acc[i][j][r] + bc) * scale);
            }
        }
}

// ---------------------------------------------------------------- attention
// Token-sliced S^T = K Q^T: wave owns a 16-token A-slice (K read once),
// Q held in regs as B-frags for whole kernel, P written as packed b64 to
// block-shared LDS, PV reads P rows + V^T tokpairs. 2 barriers/iter.
__global__ __launch_bounds__(256, 3) void attn_kernel(const u16* __restrict__ qkv,
                                                      float* __restrict__ out) {
    const int T = 2048, C3 = 2304, Cc = 768, Dh = 64;

    // balanced decode: co-resident blocks (stride 256) get qa = {x, 15-x, (x+8)&15}
    const int bid = blockIdx.x;
    const int rr = bid >> 8;
    const int ss = bid & 255;
    const int x = ss & 15;
    const int qa = (rr == 0) ? x : (rr == 1) ? (15 - x) : ((x + 8) & 15);
    const int qb = 31 - qa;
    const int hb = (ss >> 4) + (rr << 4);
    const int h = hb % 12, b = hb / 12;

    const int t = threadIdx.x;
    const int wave = t >> 6, lane = t & 63;
    const int quad = lane >> 4, l16 = lane & 15;

    __shared__ __align__(16) u16 sK[2][64 * 64];    // 16 KB, chunk ^= row&7
    __shared__ __align__(16) u32 sVt[2][64 * 36];   // 18 KB, [d][tokpair]
    __shared__ __align__(16) u16 sP[128 * 72];      // 18 KB, [q 0-63 tile a, 64-127 tile b][tok]

    const u16* qbase = qkv + (size_t)b * T * C3 + (size_t)h * Dh;
    const u16* kbase = qbase + Cc;
    const u16* vbase = qbase + 2 * Cc;

    // Q B-frags held in regs: qf[cg][half] = Q[q = tile(cg) + (cg&3)*16 + l16][d half]
    bf16x8 qf[8][2];
    #pragma unroll
    for (int cg = 0; cg < 8; ++cg) {
        const int qrow = ((cg < 4) ? qa * 64 : (qb * 64 - 64)) + cg * 16 + l16;
        const u16* p = qbase + (size_t)qrow * C3 + quad * 8;
        qf[cg][0] = ldfrag(p);
        qf[cg][1] = ldfrag(p + 32);
    }

    // O acc: group 0 = tile-a rows wave*16.., group 1 = tile-b rows wave*16..
    f32x4 oacc[2][4] = {};

    const int tp = t & 31, dg = t >> 5;            // V staging
    const int krow_b = wave * 8 + (lane >> 3);     // K staging (+ j*32)
    const int kswz = (lane >> 3) & 7;
    const int kch = (lane & 7) ^ kswz;

    int4 v0r, v1r;
    auto loadV = [&](int it) {
        const u16* vp = vbase + (size_t)(it * 64 + 2 * tp) * C3 + dg * 8;
        v0r = ldg16(vp);
        v1r = ldg16(vp + C3);
    };
    auto stageK = [&](int it, int bi) {
        #pragma unroll
        for (int j = 0; j < 2; ++j)
            async16(&sK[bi][0] + j * 2048 + wave * 512,
                    kbase + (size_t)(it * 64 + j * 32 + krow_b) * C3 + kch * 8);
    };
    auto writeV = [&](int bi) {
        union { int4 v; u16 e[8]; } ua, ub;
        ua.v = v0r; ub.v = v1r;
        #pragma unroll
        for (int i = 0; i < 8; ++i)
            sVt[bi][(dg * 8 + i) * 36 + tp] = (u32)ua.e[i] | ((u32)ub.e[i] << 16);
    };

    loadV(0);
    stageK(0, 0);
    writeV(0);
    __syncthreads();

    int buf = 0;
    for (int it = 0; it <= qb; ++it) {
        const bool more = (it < qb);
        if (more) { loadV(it + 1); stageK(it + 1, buf ^ 1); }

        const bool act_a = (it <= qa);

        // ---- QK: A = this wave's 16-token K slice (2 reads), B = Q regs
        bf16x8 kf0, kf1;
        {
            const u16* kr = &sK[buf][0] + (wave * 16 + l16) * 64;
            const int rsw = l16 & 7;
            kf0 = ldfrag(kr + ((quad ^ rsw) << 3));
            kf1 = ldfrag(kr + (((quad + 4) ^ rsw) << 3));
        }
        const int cg_lo = act_a ? 0 : 4;
        #pragma unroll
        for (int cg = 7; cg >= 0; --cg) {           // b tiles first (always active)
            if (cg < cg_lo) break;
            f32x4 s = {};
            s = __builtin_amdgcn_mfma_f32_16x16x32_bf16(kf0, qf[cg][0], s, 0, 0, 0);
            s = __builtin_amdgcn_mfma_f32_16x16x32_bf16(kf1, qf[cg][1], s, 0, 0, 0);
            const bool diag = (cg < 4) ? (it == qa) : (it == qb);
            u32 bits[4];
            #pragma unroll
            for (int r = 0; r < 4; ++r) {
                float v = fmaxf(s[r], 0.0f);
                if (diag && (wave * 16 + quad * 4 + r > (cg & 3) * 16 + l16)) v = 0.0f;
                bits[r] = __builtin_bit_cast(u32, v);
            }
            // trunc-pack 4 bf16 -> b64 (P >= 0; trunc err ~0.2% rel, within budget)
            u32 pk[2];
            pk[0] = (bits[1] & 0xFFFF0000u) | (bits[0] >> 16);
            pk[1] = (bits[3] & 0xFFFF0000u) | (bits[2] >> 16);
            __builtin_memcpy((u16*)__builtin_assume_aligned(
                                 sP + (cg * 16 + l16) * 72 + wave * 16 + quad * 4, 8),
                             pk, 8);
        }
        __syncthreads();   // P visible to all waves (also drains K async / V loads)

        // ---- PV: O[g] += P[rows] @ V^T
        const u16* sVb = (const u16*)sVt[buf];
        #pragma unroll
        for (int kk = 0; kk < 2; ++kk) {
            bf16x8 ap1 = ldfrag(sP + (64 + wave * 16 + l16) * 72 + kk * 32 + quad * 8);
            bf16x8 ap0;
            if (act_a) ap0 = ldfrag(sP + (wave * 16 + l16) * 72 + kk * 32 + quad * 8);
            #pragma unroll
            for (int dt = 0; dt < 4; ++dt) {
                bf16x8 bv = ldfrag(sVb + (dt * 16 + l16) * 72 + kk * 32 + quad * 8);
                oacc[1][dt] = __builtin_amdgcn_mfma_f32_16x16x32_bf16(ap1, bv, oacc[1][dt], 0, 0, 0);
                if (act_a)
                    oacc[0][dt] = __builtin_amdgcn_mfma_f32_16x16x32_bf16(ap0, bv, oacc[0][dt], 0, 0, 0);
            }
        }

        if (more) writeV(buf ^ 1);
        __syncthreads();   // V(it+1) visible; P safe to overwrite next iter
        buf ^= 1;
    }

    // ---- write O (fp32, C/D layout): row m = quad*4+r, col = l16
    #pragma unroll
    for (int g = 0; g < 2; ++g)
        #pragma unroll
        for (int dt = 0; dt < 4; ++dt)
            #pragma unroll
            for (int r = 0; r < 4; ++r) {
                const int tok = (g == 0 ? qa * 64 : qb * 64) + wave * 16 + quad * 4 + r;
                const int c = h * Dh + dt * 16 + l16;
                out[((size_t)b * T + tok) * Cc + c] = oacc[g][dt][r];
            }
}

// ---------------------------------------------------------------- launch
extern "C" void kernel_launch(void* const* d_in, const int* in_sizes, int n_in,
                              void* d_out, int out_size, void* d_ws, size_t ws_size,
                              hipStream_t stream) {
    const float* x    = (const float*)d_in[0];   // [4,2048,768]
    const float* W    = (const float*)d_in[1];   // [768,2304]
    const float* bias = (const float*)d_in[2];   // [2304]
    float* out = (float*)d_out;                  // [4,2048,768]

    char* ws = (char*)d_ws;
    const size_t xb_bytes = (size_t)8192 * 768 * 2;
    const size_t wt_bytes = (size_t)2304 * 768 * 2;
    u16* xb  = (u16*)ws;
    u16* Wt  = (u16*)(ws + xb_bytes);
    u16* qkv = (u16*)(ws + xb_bytes + wt_bytes);

    cvt_bf16<<<6144, 256, 0, stream>>>(x, xb, 8192 * 768);
    wt_transpose<<<dim3(72, 24), 256, 0, stream>>>(W, Wt);
    qkv_gemm<<<dim3(18, 64), 256, 0, stream>>>(xb, Wt, bias, qkv);
    attn_kernel<<<768, 256, 0, stream>>>(qkv, out);
}